// Round 2
// baseline (926.119 us; speedup 1.0000x reference)
//
#include <hip/hip_runtime.h>
#include <hip/hip_bf16.h>

typedef __attribute__((ext_vector_type(4))) float f32x4;
typedef __attribute__((ext_vector_type(8))) short short8;

#define DEVI __device__ __forceinline__

DEVI unsigned short f2bf(float x) {
  union { float f; unsigned u; } v; v.f = x;
  unsigned r = v.u + 0x7fffu + ((v.u >> 16) & 1u);
  return (unsigned short)(r >> 16);
}
DEVI float bf2f(unsigned short h) {
  union { unsigned u; float f; } v; v.u = ((unsigned)h) << 16;
  return v.f;
}
DEVI short8 pack8(f32x4 lo, f32x4 hi) {
  short8 r;
  r[0] = (short)f2bf(lo[0]); r[1] = (short)f2bf(lo[1]);
  r[2] = (short)f2bf(lo[2]); r[3] = (short)f2bf(lo[3]);
  r[4] = (short)f2bf(hi[0]); r[5] = (short)f2bf(hi[1]);
  r[6] = (short)f2bf(hi[2]); r[7] = (short)f2bf(hi[3]);
  return r;
}

DEVI void gld16(const void* g, void* l) {
  __builtin_amdgcn_global_load_lds(
      (const __attribute__((address_space(1))) void*)g,
      (__attribute__((address_space(3))) void*)l, 16, 0, 0);
}

// ---------- prep: fp32 -> bf16 for W_hh0, W_hh1, W_ih1, W_ih0 ----------
__global__ __launch_bounds__(256) void prep_cvt(
    const float* __restrict__ whh0, const float* __restrict__ whh1,
    const float* __restrict__ wih1, const float* __restrict__ wih0,
    short* __restrict__ o_whh0, short* __restrict__ o_whh1,
    short* __restrict__ o_wih1, short* __restrict__ o_wih0) {
  int i = blockIdx.x * 256 + threadIdx.x;
  if (i < 262144) { o_whh0[i] = (short)f2bf(whh0[i]); return; }
  if (i < 524288) { int j = i - 262144; o_whh1[j] = (short)f2bf(whh1[j]); return; }
  if (i < 786432) { int j = i - 524288; o_wih1[j] = (short)f2bf(wih1[j]); return; }
  if (i < 917504) { int j = i - 786432; o_wih0[j] = (short)f2bf(wih0[j]); return; }
}

// ---------- GEMM: pre = A @ W^T + bias_a + bias_b  (bf16 out) ----------
// A rows: GATHER -> embed[x[n,t]] (fp32, cvt on the fly);  else bf16 [65536][KDIM]
// B: [512][KDIM] bf16 (pre-converted).
// out: [65536][512] bf16.  Tile 128x128, BK=64, 256 threads (2x2 waves of 64x64).
template<int KDIM, bool GATHER>
__global__ __launch_bounds__(256) void gemm_pre(
    const float* __restrict__ embed, const int* __restrict__ xtok,
    const short* __restrict__ Abf, const short* __restrict__ Bbf,
    const float* __restrict__ bias_a, const float* __restrict__ bias_b,
    short* __restrict__ out) {
  __shared__ short smem[16384];          // As[128][64] @0, Bs[128][64] @8192 (shorts)
  short* As = smem;
  short* Bs = smem + 8192;

  const int tid = threadIdx.x;
  const int bM = (int)blockIdx.x >> 2;   // 512 M-tiles
  const int bN = (int)blockIdx.x & 3;    // 4 N-tiles
  const int m0 = bM * 128, n0 = bN * 128;

  f32x4 acc[4][4];
#pragma unroll
  for (int i = 0; i < 4; ++i)
#pragma unroll
    for (int j = 0; j < 4; ++j) acc[i][j] = (f32x4){0.f, 0.f, 0.f, 0.f};

  const int lane = tid & 63, wid = tid >> 6;
  const int wm = wid >> 1, wn = wid & 1;
  const int l15 = lane & 15, lk = lane >> 4;

  // staging: thread -> (row 0..127, k-half 0/32)
  const int srow = tid >> 1;
  const int skh = (tid & 1) * 32;
  const int sxor = (srow & 7) << 4;
  const int sbyte0 = srow * 128 + skh * 2;

  const float* aG = nullptr;
  const short* aB = nullptr;
  if (GATHER) {
    int r = m0 + srow;
    int t = r >> 11, n = r & 2047;
    int tok = xtok[(n << 5) + t];
    aG = embed + (size_t)tok * 256;
  } else {
    aB = Abf + (size_t)(m0 + srow) * KDIM;
  }
  const short* bRow = Bbf + (size_t)(n0 + srow) * KDIM;

  for (int kb = 0; kb < KDIM; kb += 64) {
    __syncthreads();
#pragma unroll
    for (int c = 0; c < 4; ++c) {
      short8 pa;
      if (GATHER) {
        const float* src = aG + kb + skh + c * 8;
        f32x4 lo = *(const f32x4*)(src);
        f32x4 hi = *(const f32x4*)(src + 4);
        pa = pack8(lo, hi);
      } else {
        pa = *(const short8*)(aB + kb + skh + c * 8);
      }
      *(short8*)((char*)As + ((sbyte0 + c * 16) ^ sxor)) = pa;
      short8 pb = *(const short8*)(bRow + kb + skh + c * 8);
      *(short8*)((char*)Bs + ((sbyte0 + c * 16) ^ sxor)) = pb;
    }
    __syncthreads();
#pragma unroll
    for (int kt = 0; kt < 2; ++kt) {
      short8 av[4], bv[4];
#pragma unroll
      for (int mi = 0; mi < 4; ++mi) {
        int row = wm * 64 + mi * 16 + l15;
        int off = (row * 128 + kt * 64 + lk * 16) ^ ((row & 7) << 4);
        av[mi] = *(const short8*)((const char*)As + off);
      }
#pragma unroll
      for (int ni = 0; ni < 4; ++ni) {
        int col = wn * 64 + ni * 16 + l15;
        int off = (col * 128 + kt * 64 + lk * 16) ^ ((col & 7) << 4);
        bv[ni] = *(const short8*)((const char*)Bs + off);
      }
#pragma unroll
      for (int mi = 0; mi < 4; ++mi)
#pragma unroll
        for (int ni = 0; ni < 4; ++ni)
          acc[mi][ni] = __builtin_amdgcn_mfma_f32_16x16x32_bf16(av[mi], bv[ni], acc[mi][ni], 0, 0, 0);
    }
  }
  __syncthreads();
  float bsum[4];
#pragma unroll
  for (int ni = 0; ni < 4; ++ni) {
    int cg = n0 + wn * 64 + ni * 16 + l15;
    bsum[ni] = bias_a[cg] + bias_b[cg];
  }
  short* Cs = smem;
#pragma unroll
  for (int mi = 0; mi < 4; ++mi)
#pragma unroll
    for (int ni = 0; ni < 4; ++ni)
#pragma unroll
      for (int r = 0; r < 4; ++r) {
        int row = wm * 64 + mi * 16 + lk * 4 + r;
        int col = wn * 64 + ni * 16 + l15;
        Cs[row * 128 + col] = (short)f2bf(acc[mi][ni][r] + bsum[ni]);
      }
  __syncthreads();
  {
    int row = tid >> 1, colh = (tid & 1) * 64;
    size_t gbase = (size_t)(m0 + row) * 512 + n0 + colh;
#pragma unroll
    for (int c = 0; c < 8; ++c)
      *(short8*)(out + gbase + c * 8) = *(const short8*)&Cs[row * 128 + colh + c * 8];
  }
}

// ---------- recurrence: h_t = relu(pre_t + h_{t-1} @ W_hh^T) ----------
// 128 blocks x 1024 threads (16 waves). Wave w owns output cols [32w, 32w+32).
// k<256 of W_hh register-stationary (64 VGPRs); k in [256,512) streamed from L2
// each step via global_load_lds into a wave-private 4-slot LDS ring with
// hand-counted vmcnt (never drained to 0 in the loop).
template<bool WRITE_OUTS>
__global__ __launch_bounds__(1024) void recur(
    const short* __restrict__ pre,   // [32][2048][512] bf16
    const short* __restrict__ Wbf,   // [512][512] bf16
    short* __restrict__ outs,        // [32][2048][512] bf16 (WRITE_OUTS)
    float* __restrict__ hlast) {     // [2048][512] f32 (!WRITE_OUTS)
  __shared__ __align__(16) char lds[147456];  // hbuf[16][512]bf16 @0 (swizzled); ring @16384
  const int tid = threadIdx.x;
  const int lane = tid & 63, wid = tid >> 6;
  const int l15 = lane & 15, lk = lane >> 4;
  const int n0 = (int)blockIdx.x * 16;

  // stationary W frags: kt 0..7  (k = kt*32 + lk*8, col = wid*32 + f*16 + l15)
  short8 wf[8][2];
  const short* wcol = Wbf + (size_t)(wid * 32 + l15) * 512 + lk * 8;
#pragma unroll
  for (int kt = 0; kt < 8; ++kt)
#pragma unroll
    for (int f = 0; f < 2; ++f)
      wf[kt][f] = *(const short8*)(wcol + f * (16 * 512) + kt * 32);

  const short* wsrc = wcol + 256;                // streamed source, chunk c at +c*32, f at +f*8192
  char* ring = lds + 16384 + wid * 8192;         // wave-private: 4 slots x 2KB (f0 1KB | f1 1KB)

  // prologue: issue chunks 0..3 into slots 0..3  (8 gld_lds in flight)
#pragma unroll
  for (int c = 0; c < 4; ++c) {
    gld16(wsrc + c * 32, ring + c * 2048);
    gld16(wsrc + 8192 + c * 32, ring + c * 2048 + 1024);
  }

  // zero h(-1)
  {
    short8 z = {0, 0, 0, 0, 0, 0, 0, 0};
    *(short8*)(lds + tid * 16) = z;
  }
  __syncthreads();

  const short* pb = pre + (size_t)(n0 + lk * 4) * 512 + wid * 32 + l15;
  const int arow = l15 * 1024;
  const int axr = l15 & 7;
  const int col0 = wid * 32 + l15;

#pragma unroll 1
  for (int t = 0; t < 32; ++t) {
    // pre loads for the epilogue (8 scalar bf16, per-lane; issued early, used late)
    unsigned short pvA[4], pvB[4];
    {
      const short* pt = pb + (size_t)t * (2048 * 512);
#pragma unroll
      for (int r = 0; r < 4; ++r) {
        pvA[r] = *(const unsigned short*)(pt + r * 512);
        pvB[r] = *(const unsigned short*)(pt + r * 512 + 16);
      }
    }
    asm volatile("" ::: "memory");
    __builtin_amdgcn_sched_barrier(0);

    f32x4 acc0 = {0.f, 0.f, 0.f, 0.f}, acc1 = {0.f, 0.f, 0.f, 0.f};

    // streamed first half: chunks 0..3 (kt 8..11); refill slots with chunks 4..7
#pragma unroll
    for (int c = 0; c < 4; ++c) {
      asm volatile("s_waitcnt vmcnt(14)" ::: "memory");
      __builtin_amdgcn_sched_barrier(0);
      const char* slot = ring + c * 2048;
      short8 b0 = *(const short8*)(slot + lane * 16);
      short8 b1 = *(const short8*)(slot + 1024 + lane * 16);
      short8 a = *(const short8*)(lds + arow + ((((8 + c) * 4 + lk) ^ axr) << 4));
      acc0 = __builtin_amdgcn_mfma_f32_16x16x32_bf16(a, b0, acc0, 0, 0, 0);
      acc1 = __builtin_amdgcn_mfma_f32_16x16x32_bf16(a, b1, acc1, 0, 0, 0);
      asm volatile("s_waitcnt lgkmcnt(0)" ::: "memory");
      __builtin_amdgcn_sched_barrier(0);
      gld16(wsrc + (c + 4) * 32, (char*)slot);
      gld16(wsrc + 8192 + (c + 4) * 32, (char*)slot + 1024);
    }

    // stationary: kt 0..7 from registers
#pragma unroll
    for (int kt = 0; kt < 8; ++kt) {
      short8 a = *(const short8*)(lds + arow + (((kt * 4 + lk) ^ axr) << 4));
      acc0 = __builtin_amdgcn_mfma_f32_16x16x32_bf16(a, wf[kt][0], acc0, 0, 0, 0);
      acc1 = __builtin_amdgcn_mfma_f32_16x16x32_bf16(a, wf[kt][1], acc1, 0, 0, 0);
    }

    // streamed second half: chunks 4..7 (kt 12..15); refill with next step's 0..3
#pragma unroll
    for (int c = 4; c < 8; ++c) {
      asm volatile("s_waitcnt vmcnt(6)" ::: "memory");
      __builtin_amdgcn_sched_barrier(0);
      const char* slot = ring + (c - 4) * 2048;
      short8 b0 = *(const short8*)(slot + lane * 16);
      short8 b1 = *(const short8*)(slot + 1024 + lane * 16);
      short8 a = *(const short8*)(lds + arow + ((((8 + c) * 4 + lk) ^ axr) << 4));
      acc0 = __builtin_amdgcn_mfma_f32_16x16x32_bf16(a, b0, acc0, 0, 0, 0);
      acc1 = __builtin_amdgcn_mfma_f32_16x16x32_bf16(a, b1, acc1, 0, 0, 0);
      asm volatile("s_waitcnt lgkmcnt(0)" ::: "memory");
      __builtin_amdgcn_sched_barrier(0);
      gld16(wsrc + (c - 4) * 32, (char*)slot);
      gld16(wsrc + 8192 + (c - 4) * 32, (char*)slot + 1024);
    }

    // store h(t-1) to outs (reads hbuf; must precede barrier#1)
    if (WRITE_OUTS && t > 0) {
      short8 v = *(const short8*)(lds + wid * 1024 + (lane >> 3) * 128 +
                                  (((lane & 7) ^ (wid & 7)) << 4));
      *(short8*)(outs + ((size_t)(t - 1) * 2048 + n0 + wid) * 512 + lane * 8) = v;
    }

    __syncthreads();  // barrier#1: all reads of h(t-1) complete

    // epilogue: h(t) = relu(acc + pre), written in place (XOR-swizzled)
#pragma unroll
    for (int r = 0; r < 4; ++r) {
      int row = lk * 4 + r;
      float v0 = fmaxf(acc0[r] + bf2f(pvA[r]), 0.f);
      float v1 = fmaxf(acc1[r] + bf2f(pvB[r]), 0.f);
      int g0 = col0 >> 3;
      *(short*)(lds + row * 1024 + ((g0 ^ (row & 7)) << 4) + (col0 & 7) * 2) = (short)f2bf(v0);
      *(short*)(lds + row * 1024 + (((g0 + 2) ^ (row & 7)) << 4) + (col0 & 7) * 2) = (short)f2bf(v1);
      if (!WRITE_OUTS && t == 31) {
        hlast[(size_t)(n0 + row) * 512 + col0] = v0;
        hlast[(size_t)(n0 + row) * 512 + col0 + 16] = v1;
      }
    }
    __syncthreads();  // barrier#2: h(t) visible to all
  }

  if (WRITE_OUTS) {
    short8 v = *(const short8*)(lds + wid * 1024 + (lane >> 3) * 128 +
                                (((lane & 7) ^ (wid & 7)) << 4));
    *(short8*)(outs + ((size_t)31 * 2048 + n0 + wid) * 512 + lane * 8) = v;
  }
}

// ---------- head: s[b,n] = h_n.(wl-wg) + (sum_n h).wg + b_pred ----------
__global__ __launch_bounds__(512) void predict(
    const float* __restrict__ h1, const float* __restrict__ Wp,
    const float* __restrict__ bp, float* __restrict__ out) {
  const int b = blockIdx.x, tid = threadIdx.x;
  const int lane = tid & 63, wid = tid >> 6;
  __shared__ float red[8];
  __shared__ float sgd_s;
  const float* hb = h1 + (size_t)b * 256 * 512;
  float s = 0.f;
  for (int n = 0; n < 256; ++n) s += hb[(size_t)n * 512 + tid];
  float p = s * Wp[512 + tid];
#pragma unroll
  for (int o = 32; o; o >>= 1) p += __shfl_xor(p, o);
  if (lane == 0) red[wid] = p;
  __syncthreads();
  if (tid == 0) {
    float q = 0.f;
#pragma unroll
    for (int i = 0; i < 8; ++i) q += red[i];
    sgd_s = q;
  }
  __syncthreads();
  const float sgd = sgd_s + bp[0];
  float wd[8];
  const int k0 = lane * 8;
#pragma unroll
  for (int j = 0; j < 8; ++j) wd[j] = Wp[k0 + j] - Wp[512 + k0 + j];
  for (int c = 0; c < 32; ++c) {
    int n = wid * 32 + c;
    const float* hr = hb + (size_t)n * 512 + k0;
    float d = 0.f;
#pragma unroll
    for (int j = 0; j < 8; ++j) d += hr[j] * wd[j];
#pragma unroll
    for (int o = 1; o < 64; o <<= 1) d += __shfl_xor(d, o);
    if (lane == 0) out[b * 256 + n] = d + sgd;
  }
}

extern "C" void kernel_launch(void* const* d_in, const int* in_sizes, int n_in,
                              void* d_out, int out_size, void* d_ws, size_t ws_size,
                              hipStream_t stream) {
  const int* x = (const int*)d_in[0];
  const float* embed = (const float*)d_in[1];
  const float* Wih0 = (const float*)d_in[2];
  const float* Whh0 = (const float*)d_in[3];
  const float* bih0 = (const float*)d_in[4];
  const float* bhh0 = (const float*)d_in[5];
  const float* Wih1 = (const float*)d_in[6];
  const float* Whh1 = (const float*)d_in[7];
  const float* bih1 = (const float*)d_in[8];
  const float* bhh1 = (const float*)d_in[9];
  const float* Wpred = (const float*)d_in[10];
  const float* bpred = (const float*)d_in[11];
  float* out = (float*)d_out;

  char* ws = (char*)d_ws;
  short* whh0_bf = (short*)ws;                          // 512 KB
  short* whh1_bf = (short*)(ws + 524288);               // 512 KB
  short* wih0_bf = (short*)(ws + 1048576);              // 256 KB
  short* wih1_bf = (short*)(ws + 1310720);              // 512 KB
  short* pre     = (short*)(ws + 2097152);              // 64 MB (pre0, then pre1)
  short* outs0   = (short*)(ws + 2097152 + 67108864);   // 64 MB
  float* h1      = (float*)(ws + 2097152 + 2ll * 67108864);  // 4 MB

  prep_cvt<<<3584, 256, 0, stream>>>(Whh0, Whh1, Wih1, Wih0,
                                     whh0_bf, whh1_bf, wih1_bf, wih0_bf);
  gemm_pre<256, true><<<2048, 256, 0, stream>>>(embed, x, nullptr, wih0_bf, bih0, bhh0, pre);
  recur<true><<<128, 1024, 0, stream>>>(pre, whh0_bf, outs0, nullptr);
  gemm_pre<512, false><<<2048, 256, 0, stream>>>(nullptr, nullptr, outs0, wih1_bf, bih1, bhh1, pre);
  recur<false><<<128, 1024, 0, stream>>>(pre, whh1_bf, nullptr, h1);
  predict<<<8, 512, 0, stream>>>(h1, Wpred, bpred, out);
}

// Round 3
// 610.826 us; speedup vs baseline: 1.5162x; 1.5162x over previous
//
#include <hip/hip_runtime.h>
#include <hip/hip_bf16.h>

typedef __attribute__((ext_vector_type(4))) float f32x4;
typedef __attribute__((ext_vector_type(8))) short short8;

#define DEVI __device__ __forceinline__

DEVI unsigned short f2bf(float x) {
  union { float f; unsigned u; } v; v.f = x;
  unsigned r = v.u + 0x7fffu + ((v.u >> 16) & 1u);
  return (unsigned short)(r >> 16);
}
DEVI float bf2f(unsigned short h) {
  union { unsigned u; float f; } v; v.u = ((unsigned)h) << 16;
  return v.f;
}
DEVI short8 pack8(f32x4 lo, f32x4 hi) {
  short8 r;
  r[0] = (short)f2bf(lo[0]); r[1] = (short)f2bf(lo[1]);
  r[2] = (short)f2bf(lo[2]); r[3] = (short)f2bf(lo[3]);
  r[4] = (short)f2bf(hi[0]); r[5] = (short)f2bf(hi[1]);
  r[6] = (short)f2bf(hi[2]); r[7] = (short)f2bf(hi[3]);
  return r;
}

// ---------- prep: fp32 -> bf16 for W_hh0, W_hh1, W_ih1, W_ih0 ----------
__global__ __launch_bounds__(256) void prep_cvt(
    const float* __restrict__ whh0, const float* __restrict__ whh1,
    const float* __restrict__ wih1, const float* __restrict__ wih0,
    short* __restrict__ o_whh0, short* __restrict__ o_whh1,
    short* __restrict__ o_wih1, short* __restrict__ o_wih0) {
  int i = blockIdx.x * 256 + threadIdx.x;
  if (i < 262144) { o_whh0[i] = (short)f2bf(whh0[i]); return; }
  if (i < 524288) { int j = i - 262144; o_whh1[j] = (short)f2bf(whh1[j]); return; }
  if (i < 786432) { int j = i - 524288; o_wih1[j] = (short)f2bf(wih1[j]); return; }
  if (i < 917504) { int j = i - 786432; o_wih0[j] = (short)f2bf(wih0[j]); return; }
}

// ---------- GEMM: pre = A @ W^T + bias_a + bias_b  (bf16 out) ----------
template<int KDIM, bool GATHER>
__global__ __launch_bounds__(256) void gemm_pre(
    const float* __restrict__ embed, const int* __restrict__ xtok,
    const short* __restrict__ Abf, const short* __restrict__ Bbf,
    const float* __restrict__ bias_a, const float* __restrict__ bias_b,
    short* __restrict__ out) {
  __shared__ short smem[16384];          // As[128][64] @0, Bs[128][64] @8192 (shorts)
  short* As = smem;
  short* Bs = smem + 8192;

  const int tid = threadIdx.x;
  const int bM = (int)blockIdx.x >> 2;
  const int bN = (int)blockIdx.x & 3;
  const int m0 = bM * 128, n0 = bN * 128;

  f32x4 acc[4][4];
#pragma unroll
  for (int i = 0; i < 4; ++i)
#pragma unroll
    for (int j = 0; j < 4; ++j) acc[i][j] = (f32x4){0.f, 0.f, 0.f, 0.f};

  const int lane = tid & 63, wid = tid >> 6;
  const int wm = wid >> 1, wn = wid & 1;
  const int l15 = lane & 15, lk = lane >> 4;

  const int srow = tid >> 1;
  const int skh = (tid & 1) * 32;
  const int sxor = (srow & 7) << 4;
  const int sbyte0 = srow * 128 + skh * 2;

  const float* aG = nullptr;
  const short* aB = nullptr;
  if (GATHER) {
    int r = m0 + srow;
    int t = r >> 11, n = r & 2047;
    int tok = xtok[(n << 5) + t];
    aG = embed + (size_t)tok * 256;
  } else {
    aB = Abf + (size_t)(m0 + srow) * KDIM;
  }
  const short* bRow = Bbf + (size_t)(n0 + srow) * KDIM;

  for (int kb = 0; kb < KDIM; kb += 64) {
    __syncthreads();
#pragma unroll
    for (int c = 0; c < 4; ++c) {
      short8 pa;
      if (GATHER) {
        const float* src = aG + kb + skh + c * 8;
        f32x4 lo = *(const f32x4*)(src);
        f32x4 hi = *(const f32x4*)(src + 4);
        pa = pack8(lo, hi);
      } else {
        pa = *(const short8*)(aB + kb + skh + c * 8);
      }
      *(short8*)((char*)As + ((sbyte0 + c * 16) ^ sxor)) = pa;
      short8 pb = *(const short8*)(bRow + kb + skh + c * 8);
      *(short8*)((char*)Bs + ((sbyte0 + c * 16) ^ sxor)) = pb;
    }
    __syncthreads();
#pragma unroll
    for (int kt = 0; kt < 2; ++kt) {
      short8 av[4], bv[4];
#pragma unroll
      for (int mi = 0; mi < 4; ++mi) {
        int row = wm * 64 + mi * 16 + l15;
        int off = (row * 128 + kt * 64 + lk * 16) ^ ((row & 7) << 4);
        av[mi] = *(const short8*)((const char*)As + off);
      }
#pragma unroll
      for (int ni = 0; ni < 4; ++ni) {
        int col = wn * 64 + ni * 16 + l15;
        int off = (col * 128 + kt * 64 + lk * 16) ^ ((col & 7) << 4);
        bv[ni] = *(const short8*)((const char*)Bs + off);
      }
#pragma unroll
      for (int mi = 0; mi < 4; ++mi)
#pragma unroll
        for (int ni = 0; ni < 4; ++ni)
          acc[mi][ni] = __builtin_amdgcn_mfma_f32_16x16x32_bf16(av[mi], bv[ni], acc[mi][ni], 0, 0, 0);
    }
  }
  __syncthreads();
  float bsum[4];
#pragma unroll
  for (int ni = 0; ni < 4; ++ni) {
    int cg = n0 + wn * 64 + ni * 16 + l15;
    bsum[ni] = bias_a[cg] + bias_b[cg];
  }
  short* Cs = smem;
#pragma unroll
  for (int mi = 0; mi < 4; ++mi)
#pragma unroll
    for (int ni = 0; ni < 4; ++ni)
#pragma unroll
      for (int r = 0; r < 4; ++r) {
        int row = wm * 64 + mi * 16 + lk * 4 + r;
        int col = wn * 64 + ni * 16 + l15;
        Cs[row * 128 + col] = (short)f2bf(acc[mi][ni][r] + bsum[ni]);
      }
  __syncthreads();
  {
    int row = tid >> 1, colh = (tid & 1) * 64;
    size_t gbase = (size_t)(m0 + row) * 512 + n0 + colh;
#pragma unroll
    for (int c = 0; c < 8; ++c)
      *(short8*)(out + gbase + c * 8) = *(const short8*)&Cs[row * 128 + colh + c * 8];
  }
}

// ---------- recurrence: h_t = relu(pre_t + h_{t-1} @ W_hh^T) ----------
// 128 blocks x 512 threads (8 waves, 2/SIMD). Wave w owns cols [64w, 64w+64).
// Full W_hh slice register-stationary: wf[16][4] = 256 VGPRs, granted by
// __launch_bounds__(512, 2). No inline asm, no global_load_lds.
template<bool WRITE_OUTS>
__global__ __launch_bounds__(512, 2) void recur(
    const short* __restrict__ pre,   // [32][2048][512] bf16
    const short* __restrict__ Wbf,   // [512][512] bf16 (row h_out contiguous in k)
    short* __restrict__ outs,        // [32][2048][512] bf16 (WRITE_OUTS)
    float* __restrict__ hlast) {     // [2048][512] f32 (!WRITE_OUTS)
  __shared__ __align__(16) char hl[16 * 1024];  // h tile: 16 rows x 512 bf16, XOR-swizzled
  const int tid = threadIdx.x;
  const int lane = tid & 63, wid = tid >> 6;
  const int l15 = lane & 15, lk = lane >> 4;
  const int n0 = (int)blockIdx.x * 16;

  // stationary W fragments: wf[kt][ni] -> col = wid*64 + ni*16 + l15, k = kt*32 + lk*8
  short8 wf[16][4];
  {
    const short* wbase = Wbf + (size_t)(wid * 64 + l15) * 512 + lk * 8;
#pragma unroll
    for (int kt = 0; kt < 16; ++kt)
#pragma unroll
      for (int ni = 0; ni < 4; ++ni)
        wf[kt][ni] = *(const short8*)(wbase + (size_t)ni * (16 * 512) + kt * 32);
  }

  // zero h(-1)
  {
    short8 z = {0, 0, 0, 0, 0, 0, 0, 0};
    *(short8*)(hl + tid * 32) = z;
    *(short8*)(hl + tid * 32 + 16) = z;
  }
  __syncthreads();

  const short* pbase = pre + (size_t)(n0 + lk * 4) * 512 + wid * 64 + l15;
  const int crow = tid >> 5;          // outs-copy: row 0..15
  const int cseg = tid & 31;          // outs-copy: 32B segment
  const int cxor = (crow & 7) << 4;

#pragma unroll 1
  for (int t = 0; t < 32; ++t) {
    // epilogue pre values (16 scalar bf16 per lane), issued early
    unsigned short pv[4][4];
    {
      const short* pt = pbase + (size_t)t * (2048 * 512);
#pragma unroll
      for (int r = 0; r < 4; ++r)
#pragma unroll
        for (int ni = 0; ni < 4; ++ni)
          pv[r][ni] = *(const unsigned short*)(pt + r * 512 + ni * 16);
    }

    // stream h(t-1) to outs (LDS read; must precede barrier)
    if (WRITE_OUTS && t > 0) {
      short8 v0 = *(const short8*)(hl + crow * 1024 + ((cseg * 32) ^ cxor));
      short8 v1 = *(const short8*)(hl + crow * 1024 + ((cseg * 32 + 16) ^ cxor));
      short* dst = outs + ((size_t)(t - 1) * 2048 + n0 + crow) * 512 + cseg * 16;
      *(short8*)dst = v0;
      *(short8*)(dst + 8) = v1;
    }

    // MFMA: acc[ni] += A(h rows, k) * wf[kt][ni]
    f32x4 acc[4];
#pragma unroll
    for (int ni = 0; ni < 4; ++ni) acc[ni] = (f32x4){0.f, 0.f, 0.f, 0.f};
#pragma unroll
    for (int kt = 0; kt < 16; ++kt) {
      short8 a = *(const short8*)(hl + l15 * 1024 + ((kt * 64 + lk * 16) ^ ((l15 & 7) << 4)));
      acc[0] = __builtin_amdgcn_mfma_f32_16x16x32_bf16(a, wf[kt][0], acc[0], 0, 0, 0);
      acc[1] = __builtin_amdgcn_mfma_f32_16x16x32_bf16(a, wf[kt][1], acc[1], 0, 0, 0);
      acc[2] = __builtin_amdgcn_mfma_f32_16x16x32_bf16(a, wf[kt][2], acc[2], 0, 0, 0);
      acc[3] = __builtin_amdgcn_mfma_f32_16x16x32_bf16(a, wf[kt][3], acc[3], 0, 0, 0);
    }

    __syncthreads();  // all reads of h(t-1) complete

    // h(t) = relu(acc + pre), written in place (XOR-swizzled)
#pragma unroll
    for (int r = 0; r < 4; ++r) {
      int row = lk * 4 + r;
      int rxor = (row & 7) << 4;
#pragma unroll
      for (int ni = 0; ni < 4; ++ni) {
        int col = wid * 64 + ni * 16 + l15;
        float v = fmaxf(acc[ni][r] + bf2f(pv[r][ni]), 0.f);
        *(short*)(hl + row * 1024 + ((col * 2) ^ rxor)) = (short)f2bf(v);
        if (!WRITE_OUTS && t == 31) hlast[(size_t)(n0 + row) * 512 + col] = v;
      }
    }
    __syncthreads();  // h(t) visible to all
  }

  if (WRITE_OUTS) {
    short8 v0 = *(const short8*)(hl + crow * 1024 + ((cseg * 32) ^ cxor));
    short8 v1 = *(const short8*)(hl + crow * 1024 + ((cseg * 32 + 16) ^ cxor));
    short* dst = outs + ((size_t)31 * 2048 + n0 + crow) * 512 + cseg * 16;
    *(short8*)dst = v0;
    *(short8*)(dst + 8) = v1;
  }
}

// ---------- head: s[b,n] = h_n.(wl-wg) + (sum_n h).wg + b_pred ----------
__global__ __launch_bounds__(512) void predict(
    const float* __restrict__ h1, const float* __restrict__ Wp,
    const float* __restrict__ bp, float* __restrict__ out) {
  const int b = blockIdx.x, tid = threadIdx.x;
  const int lane = tid & 63, wid = tid >> 6;
  __shared__ float red[8];
  __shared__ float sgd_s;
  const float* hb = h1 + (size_t)b * 256 * 512;
  float s = 0.f;
  for (int n = 0; n < 256; ++n) s += hb[(size_t)n * 512 + tid];
  float p = s * Wp[512 + tid];
#pragma unroll
  for (int o = 32; o; o >>= 1) p += __shfl_xor(p, o);
  if (lane == 0) red[wid] = p;
  __syncthreads();
  if (tid == 0) {
    float q = 0.f;
#pragma unroll
    for (int i = 0; i < 8; ++i) q += red[i];
    sgd_s = q;
  }
  __syncthreads();
  const float sgd = sgd_s + bp[0];
  float wd[8];
  const int k0 = lane * 8;
#pragma unroll
  for (int j = 0; j < 8; ++j) wd[j] = Wp[k0 + j] - Wp[512 + k0 + j];
  for (int c = 0; c < 32; ++c) {
    int n = wid * 32 + c;
    const float* hr = hb + (size_t)n * 512 + k0;
    float d = 0.f;
#pragma unroll
    for (int j = 0; j < 8; ++j) d += hr[j] * wd[j];
#pragma unroll
    for (int o = 1; o < 64; o <<= 1) d += __shfl_xor(d, o);
    if (lane == 0) out[b * 256 + n] = d + sgd;
  }
}

extern "C" void kernel_launch(void* const* d_in, const int* in_sizes, int n_in,
                              void* d_out, int out_size, void* d_ws, size_t ws_size,
                              hipStream_t stream) {
  const int* x = (const int*)d_in[0];
  const float* embed = (const float*)d_in[1];
  const float* Wih0 = (const float*)d_in[2];
  const float* Whh0 = (const float*)d_in[3];
  const float* bih0 = (const float*)d_in[4];
  const float* bhh0 = (const float*)d_in[5];
  const float* Wih1 = (const float*)d_in[6];
  const float* Whh1 = (const float*)d_in[7];
  const float* bih1 = (const float*)d_in[8];
  const float* bhh1 = (const float*)d_in[9];
  const float* Wpred = (const float*)d_in[10];
  const float* bpred = (const float*)d_in[11];
  float* out = (float*)d_out;

  char* ws = (char*)d_ws;
  short* whh0_bf = (short*)ws;                          // 512 KB
  short* whh1_bf = (short*)(ws + 524288);               // 512 KB
  short* wih0_bf = (short*)(ws + 1048576);              // 256 KB
  short* wih1_bf = (short*)(ws + 1310720);              // 512 KB
  short* pre     = (short*)(ws + 2097152);              // 64 MB (pre0, then pre1)
  short* outs0   = (short*)(ws + 2097152 + 67108864);   // 64 MB
  float* h1      = (float*)(ws + 2097152 + 2ll * 67108864);  // 4 MB

  prep_cvt<<<3584, 256, 0, stream>>>(Whh0, Whh1, Wih1, Wih0,
                                     whh0_bf, whh1_bf, wih1_bf, wih0_bf);
  gemm_pre<256, true><<<2048, 256, 0, stream>>>(embed, x, nullptr, wih0_bf, bih0, bhh0, pre);
  recur<true><<<128, 512, 0, stream>>>(pre, whh0_bf, outs0, nullptr);
  gemm_pre<512, false><<<2048, 256, 0, stream>>>(nullptr, nullptr, outs0, wih1_bf, bih1, bhh1, pre);
  recur<false><<<128, 512, 0, stream>>>(pre, whh1_bf, nullptr, h1);
  predict<<<8, 512, 0, stream>>>(h1, Wpred, bpred, out);
}

// Round 4
// 584.197 us; speedup vs baseline: 1.5853x; 1.0456x over previous
//
#include <hip/hip_runtime.h>
#include <hip/hip_bf16.h>

typedef __attribute__((ext_vector_type(4))) float f32x4;
typedef __attribute__((ext_vector_type(8))) short short8;

#define DEVI __device__ __forceinline__

DEVI unsigned short f2bf(float x) {
  union { float f; unsigned u; } v; v.f = x;
  unsigned r = v.u + 0x7fffu + ((v.u >> 16) & 1u);
  return (unsigned short)(r >> 16);
}
DEVI float bf2f(unsigned short h) {
  union { unsigned u; float f; } v; v.u = ((unsigned)h) << 16;
  return v.f;
}
DEVI short8 pack8(f32x4 lo, f32x4 hi) {
  short8 r;
  r[0] = (short)f2bf(lo[0]); r[1] = (short)f2bf(lo[1]);
  r[2] = (short)f2bf(lo[2]); r[3] = (short)f2bf(lo[3]);
  r[4] = (short)f2bf(hi[0]); r[5] = (short)f2bf(hi[1]);
  r[6] = (short)f2bf(hi[2]); r[7] = (short)f2bf(hi[3]);
  return r;
}

DEVI void gld16(const void* g, void* l) {
  __builtin_amdgcn_global_load_lds(
      (const __attribute__((address_space(1))) void*)g,
      (__attribute__((address_space(3))) void*)l, 16, 0, 0);
}

// ---------- prep: fp32 -> bf16 for W_hh0, W_hh1, W_ih1, W_ih0 ----------
__global__ __launch_bounds__(256) void prep_cvt(
    const float* __restrict__ whh0, const float* __restrict__ whh1,
    const float* __restrict__ wih1, const float* __restrict__ wih0,
    short* __restrict__ o_whh0, short* __restrict__ o_whh1,
    short* __restrict__ o_wih1, short* __restrict__ o_wih0) {
  int i = blockIdx.x * 256 + threadIdx.x;
  if (i < 262144) { o_whh0[i] = (short)f2bf(whh0[i]); return; }
  if (i < 524288) { int j = i - 262144; o_whh1[j] = (short)f2bf(whh1[j]); return; }
  if (i < 786432) { int j = i - 524288; o_wih1[j] = (short)f2bf(wih1[j]); return; }
  if (i < 917504) { int j = i - 786432; o_wih0[j] = (short)f2bf(wih0[j]); return; }
}

// ---------- GEMM: pre = A @ W^T + bias_a + bias_b  (bf16 out) ----------
template<int KDIM, bool GATHER>
__global__ __launch_bounds__(256) void gemm_pre(
    const float* __restrict__ embed, const int* __restrict__ xtok,
    const short* __restrict__ Abf, const short* __restrict__ Bbf,
    const float* __restrict__ bias_a, const float* __restrict__ bias_b,
    short* __restrict__ out) {
  __shared__ short smem[16384];          // As[128][64] @0, Bs[128][64] @8192 (shorts)
  short* As = smem;
  short* Bs = smem + 8192;

  const int tid = threadIdx.x;
  const int bM = (int)blockIdx.x >> 2;
  const int bN = (int)blockIdx.x & 3;
  const int m0 = bM * 128, n0 = bN * 128;

  f32x4 acc[4][4];
#pragma unroll
  for (int i = 0; i < 4; ++i)
#pragma unroll
    for (int j = 0; j < 4; ++j) acc[i][j] = (f32x4){0.f, 0.f, 0.f, 0.f};

  const int lane = tid & 63, wid = tid >> 6;
  const int wm = wid >> 1, wn = wid & 1;
  const int l15 = lane & 15, lk = lane >> 4;

  const int srow = tid >> 1;
  const int skh = (tid & 1) * 32;
  const int sxor = (srow & 7) << 4;
  const int sbyte0 = srow * 128 + skh * 2;

  const float* aG = nullptr;
  const short* aB = nullptr;
  if (GATHER) {
    int r = m0 + srow;
    int t = r >> 11, n = r & 2047;
    int tok = xtok[(n << 5) + t];
    aG = embed + (size_t)tok * 256;
  } else {
    aB = Abf + (size_t)(m0 + srow) * KDIM;
  }
  const short* bRow = Bbf + (size_t)(n0 + srow) * KDIM;

  for (int kb = 0; kb < KDIM; kb += 64) {
    __syncthreads();
#pragma unroll
    for (int c = 0; c < 4; ++c) {
      short8 pa;
      if (GATHER) {
        const float* src = aG + kb + skh + c * 8;
        f32x4 lo = *(const f32x4*)(src);
        f32x4 hi = *(const f32x4*)(src + 4);
        pa = pack8(lo, hi);
      } else {
        pa = *(const short8*)(aB + kb + skh + c * 8);
      }
      *(short8*)((char*)As + ((sbyte0 + c * 16) ^ sxor)) = pa;
      short8 pb = *(const short8*)(bRow + kb + skh + c * 8);
      *(short8*)((char*)Bs + ((sbyte0 + c * 16) ^ sxor)) = pb;
    }
    __syncthreads();
#pragma unroll
    for (int kt = 0; kt < 2; ++kt) {
      short8 av[4], bv[4];
#pragma unroll
      for (int mi = 0; mi < 4; ++mi) {
        int row = wm * 64 + mi * 16 + l15;
        int off = (row * 128 + kt * 64 + lk * 16) ^ ((row & 7) << 4);
        av[mi] = *(const short8*)((const char*)As + off);
      }
#pragma unroll
      for (int ni = 0; ni < 4; ++ni) {
        int col = wn * 64 + ni * 16 + l15;
        int off = (col * 128 + kt * 64 + lk * 16) ^ ((col & 7) << 4);
        bv[ni] = *(const short8*)((const char*)Bs + off);
      }
#pragma unroll
      for (int mi = 0; mi < 4; ++mi)
#pragma unroll
        for (int ni = 0; ni < 4; ++ni)
          acc[mi][ni] = __builtin_amdgcn_mfma_f32_16x16x32_bf16(av[mi], bv[ni], acc[mi][ni], 0, 0, 0);
    }
  }
  __syncthreads();
  float bsum[4];
#pragma unroll
  for (int ni = 0; ni < 4; ++ni) {
    int cg = n0 + wn * 64 + ni * 16 + l15;
    bsum[ni] = bias_a[cg] + bias_b[cg];
  }
  short* Cs = smem;
#pragma unroll
  for (int mi = 0; mi < 4; ++mi)
#pragma unroll
    for (int ni = 0; ni < 4; ++ni)
#pragma unroll
      for (int r = 0; r < 4; ++r) {
        int row = wm * 64 + mi * 16 + lk * 4 + r;
        int col = wn * 64 + ni * 16 + l15;
        Cs[row * 128 + col] = (short)f2bf(acc[mi][ni][r] + bsum[ni]);
      }
  __syncthreads();
  {
    int row = tid >> 1, colh = (tid & 1) * 64;
    size_t gbase = (size_t)(m0 + row) * 512 + n0 + colh;
#pragma unroll
    for (int c = 0; c < 8; ++c)
      *(short8*)(out + gbase + c * 8) = *(const short8*)&Cs[row * 128 + colh + c * 8];
  }
}

// ---------- recurrence: h_t = relu(pre_t + h_{t-1} @ W_hh^T) ----------
// 128 blocks x 512 threads (8 waves, 2/SIMD, <=256 VGPR/wave). Wave w owns
// cols [64w, 64w+64). Hybrid W: kt 0..7 register-stationary (wf = 128 VGPR),
// kt 8..15 streamed global->VGPR each step in two 4-kt batches (64 VGPR live).
// pre tile staged to LDS via global_load_lds (no pv registers).
template<bool WRITE_OUTS>
__global__ __launch_bounds__(512, 2) void recur(
    const short* __restrict__ pre,   // [32][2048][512] bf16
    const short* __restrict__ Wbf,   // [512][512] bf16 (row h_out contiguous in k)
    short* __restrict__ outs,        // [32][2048][512] bf16 (WRITE_OUTS)
    float* __restrict__ hlast) {     // [2048][512] f32 (!WRITE_OUTS)
  __shared__ __align__(16) char hl[16384];    // h tile 16x512 bf16, XOR-swizzled
  __shared__ __align__(16) char plds[16384];  // pre tile 16x512 bf16, linear
  const int tid = threadIdx.x;
  const int lane = tid & 63, wid = tid >> 6;
  const int l15 = lane & 15, lk = lane >> 4;
  const int n0 = (int)blockIdx.x * 16;

  // per-lane W base: col = wid*64 + l15 (+ni*16 via +ni*8192 shorts), k = lk*8 (+kt*32)
  const short* wbase = Wbf + (size_t)(wid * 64 + l15) * 512 + lk * 8;

  // stationary fragments kt 0..7  (128 VGPRs)
  short8 wf[8][4];
#pragma unroll
  for (int kt = 0; kt < 8; ++kt)
#pragma unroll
    for (int ni = 0; ni < 4; ++ni)
      wf[kt][ni] = *(const short8*)(wbase + ni * 8192 + kt * 32);

  // zero h(-1)
  {
    short8 z = {0, 0, 0, 0, 0, 0, 0, 0};
    *(short8*)(hl + tid * 32) = z;
    *(short8*)(hl + tid * 32 + 16) = z;
  }
  __syncthreads();

  const int crow = tid >> 5;          // outs-copy: row 0..15
  const int cseg = tid & 31;          // outs-copy: 32B segment
  const int cxor = (crow & 7) << 4;
  const int axorbase = (l15 & 7) << 4;

#pragma unroll 1
  for (int t = 0; t < 32; ++t) {
    // stage pre tile (16 KB) -> plds; consumed after the barrier in the epilogue
    {
      const short* psrc = pre + (size_t)t * (2048 * 512) + (size_t)n0 * 512;
#pragma unroll
      for (int j = 0; j < 2; ++j) {
        int s = j * 512 + wid * 64 + lane;            // 16B slot index
        gld16(psrc + s * 8, plds + j * 8192 + wid * 1024);
      }
    }

    // batch1 streamed W: kt 8..11 (64 VGPRs live)
    short8 s1[4][4];
#pragma unroll
    for (int kt2 = 0; kt2 < 4; ++kt2)
#pragma unroll
      for (int ni = 0; ni < 4; ++ni)
        s1[kt2][ni] = *(const short8*)(wbase + ni * 8192 + (8 + kt2) * 32);

    // stream h(t-1) to outs (LDS read; must precede the epilogue barrier)
    if (WRITE_OUTS && t > 0) {
      short8 v0 = *(const short8*)(hl + crow * 1024 + ((cseg * 32) ^ cxor));
      short8 v1 = *(const short8*)(hl + crow * 1024 + ((cseg * 32 + 16) ^ cxor));
      short* dst = outs + ((size_t)(t - 1) * 2048 + n0 + crow) * 512 + cseg * 16;
      *(short8*)dst = v0;
      *(short8*)(dst + 8) = v1;
    }

    f32x4 acc[4];
#pragma unroll
    for (int ni = 0; ni < 4; ++ni) acc[ni] = (f32x4){0.f, 0.f, 0.f, 0.f};

    // stationary MFMAs kt 0..7
#pragma unroll
    for (int kt = 0; kt < 8; ++kt) {
      short8 a = *(const short8*)(hl + l15 * 1024 + ((kt * 64 + lk * 16) ^ axorbase));
      acc[0] = __builtin_amdgcn_mfma_f32_16x16x32_bf16(a, wf[kt][0], acc[0], 0, 0, 0);
      acc[1] = __builtin_amdgcn_mfma_f32_16x16x32_bf16(a, wf[kt][1], acc[1], 0, 0, 0);
      acc[2] = __builtin_amdgcn_mfma_f32_16x16x32_bf16(a, wf[kt][2], acc[2], 0, 0, 0);
      acc[3] = __builtin_amdgcn_mfma_f32_16x16x32_bf16(a, wf[kt][3], acc[3], 0, 0, 0);
    }

    // consume batch1 (kt 8..11)
#pragma unroll
    for (int kt2 = 0; kt2 < 4; ++kt2) {
      int kt = 8 + kt2;
      short8 a = *(const short8*)(hl + l15 * 1024 + ((kt * 64 + lk * 16) ^ axorbase));
      acc[0] = __builtin_amdgcn_mfma_f32_16x16x32_bf16(a, s1[kt2][0], acc[0], 0, 0, 0);
      acc[1] = __builtin_amdgcn_mfma_f32_16x16x32_bf16(a, s1[kt2][1], acc[1], 0, 0, 0);
      acc[2] = __builtin_amdgcn_mfma_f32_16x16x32_bf16(a, s1[kt2][2], acc[2], 0, 0, 0);
      acc[3] = __builtin_amdgcn_mfma_f32_16x16x32_bf16(a, s1[kt2][3], acc[3], 0, 0, 0);
    }

    __builtin_amdgcn_sched_barrier(0);  // keep batch2 loads below batch1 consumption

    // batch2 streamed W: kt 12..15
    short8 s2[4][4];
#pragma unroll
    for (int kt2 = 0; kt2 < 4; ++kt2)
#pragma unroll
      for (int ni = 0; ni < 4; ++ni)
        s2[kt2][ni] = *(const short8*)(wbase + ni * 8192 + (12 + kt2) * 32);
#pragma unroll
    for (int kt2 = 0; kt2 < 4; ++kt2) {
      int kt = 12 + kt2;
      short8 a = *(const short8*)(hl + l15 * 1024 + ((kt * 64 + lk * 16) ^ axorbase));
      acc[0] = __builtin_amdgcn_mfma_f32_16x16x32_bf16(a, s2[kt2][0], acc[0], 0, 0, 0);
      acc[1] = __builtin_amdgcn_mfma_f32_16x16x32_bf16(a, s2[kt2][1], acc[1], 0, 0, 0);
      acc[2] = __builtin_amdgcn_mfma_f32_16x16x32_bf16(a, s2[kt2][2], acc[2], 0, 0, 0);
      acc[3] = __builtin_amdgcn_mfma_f32_16x16x32_bf16(a, s2[kt2][3], acc[3], 0, 0, 0);
    }

    __syncthreads();  // all reads of h(t-1) done; plds staged (vmcnt drained)

    // epilogue: h(t) = relu(acc + pre) in place (XOR-swizzled)
#pragma unroll
    for (int r = 0; r < 4; ++r) {
      int row = lk * 4 + r;
      int rxor = (row & 7) << 4;
#pragma unroll
      for (int ni = 0; ni < 4; ++ni) {
        int col = wid * 64 + ni * 16 + l15;
        float pvf = bf2f(*(const unsigned short*)(plds + row * 1024 + col * 2));
        float v = fmaxf(acc[ni][r] + pvf, 0.f);
        *(short*)(hl + row * 1024 + ((col * 2) ^ rxor)) = (short)f2bf(v);
        if (!WRITE_OUTS && t == 31) hlast[(size_t)(n0 + row) * 512 + col] = v;
      }
    }
    __syncthreads();  // h(t) visible to all
  }

  if (WRITE_OUTS) {
    short8 v0 = *(const short8*)(hl + crow * 1024 + ((cseg * 32) ^ cxor));
    short8 v1 = *(const short8*)(hl + crow * 1024 + ((cseg * 32 + 16) ^ cxor));
    short* dst = outs + ((size_t)31 * 2048 + n0 + crow) * 512 + cseg * 16;
    *(short8*)dst = v0;
    *(short8*)(dst + 8) = v1;
  }
}

// ---------- head: s[b,n] = h_n.(wl-wg) + (sum_n h).wg + b_pred ----------
__global__ __launch_bounds__(512) void predict(
    const float* __restrict__ h1, const float* __restrict__ Wp,
    const float* __restrict__ bp, float* __restrict__ out) {
  const int b = blockIdx.x, tid = threadIdx.x;
  const int lane = tid & 63, wid = tid >> 6;
  __shared__ float red[8];
  __shared__ float sgd_s;
  const float* hb = h1 + (size_t)b * 256 * 512;
  float s = 0.f;
  for (int n = 0; n < 256; ++n) s += hb[(size_t)n * 512 + tid];
  float p = s * Wp[512 + tid];
#pragma unroll
  for (int o = 32; o; o >>= 1) p += __shfl_xor(p, o);
  if (lane == 0) red[wid] = p;
  __syncthreads();
  if (tid == 0) {
    float q = 0.f;
#pragma unroll
    for (int i = 0; i < 8; ++i) q += red[i];
    sgd_s = q;
  }
  __syncthreads();
  const float sgd = sgd_s + bp[0];
  float wd[8];
  const int k0 = lane * 8;
#pragma unroll
  for (int j = 0; j < 8; ++j) wd[j] = Wp[k0 + j] - Wp[512 + k0 + j];
  for (int c = 0; c < 32; ++c) {
    int n = wid * 32 + c;
    const float* hr = hb + (size_t)n * 512 + k0;
    float d = 0.f;
#pragma unroll
    for (int j = 0; j < 8; ++j) d += hr[j] * wd[j];
#pragma unroll
    for (int o = 1; o < 64; o <<= 1) d += __shfl_xor(d, o);
    if (lane == 0) out[b * 256 + n] = d + sgd;
  }
}

extern "C" void kernel_launch(void* const* d_in, const int* in_sizes, int n_in,
                              void* d_out, int out_size, void* d_ws, size_t ws_size,
                              hipStream_t stream) {
  const int* x = (const int*)d_in[0];
  const float* embed = (const float*)d_in[1];
  const float* Wih0 = (const float*)d_in[2];
  const float* Whh0 = (const float*)d_in[3];
  const float* bih0 = (const float*)d_in[4];
  const float* bhh0 = (const float*)d_in[5];
  const float* Wih1 = (const float*)d_in[6];
  const float* Whh1 = (const float*)d_in[7];
  const float* bih1 = (const float*)d_in[8];
  const float* bhh1 = (const float*)d_in[9];
  const float* Wpred = (const float*)d_in[10];
  const float* bpred = (const float*)d_in[11];
  float* out = (float*)d_out;

  char* ws = (char*)d_ws;
  short* whh0_bf = (short*)ws;                          // 512 KB
  short* whh1_bf = (short*)(ws + 524288);               // 512 KB
  short* wih0_bf = (short*)(ws + 1048576);              // 256 KB
  short* wih1_bf = (short*)(ws + 1310720);              // 512 KB
  short* pre     = (short*)(ws + 2097152);              // 64 MB (pre0, then pre1)
  short* outs0   = (short*)(ws + 2097152 + 67108864);   // 64 MB
  float* h1      = (float*)(ws + 2097152 + 2ll * 67108864);  // 4 MB

  prep_cvt<<<3584, 256, 0, stream>>>(Whh0, Whh1, Wih1, Wih0,
                                     whh0_bf, whh1_bf, wih1_bf, wih0_bf);
  gemm_pre<256, true><<<2048, 256, 0, stream>>>(embed, x, nullptr, wih0_bf, bih0, bhh0, pre);
  recur<true><<<128, 512, 0, stream>>>(pre, whh0_bf, outs0, nullptr);
  gemm_pre<512, false><<<2048, 256, 0, stream>>>(nullptr, nullptr, outs0, wih1_bf, bih1, bhh1, pre);
  recur<false><<<128, 512, 0, stream>>>(pre, whh1_bf, nullptr, h1);
  predict<<<8, 512, 0, stream>>>(h1, Wpred, bpred, out);
}